// Round 7
// baseline (12599.451 us; speedup 1.0000x reference)
//
#include <hip/hip_runtime.h>
#include <hip/hip_bf16.h>
#include <math.h>

#define B_    256
#define S_    128
#define EMB_  512
#define H2_   512
#define HID_  1024
#define CTX_  64
#define VOC_  32000
#define TMAX_ 40
#define SOS_  2

typedef unsigned short u16;
typedef __attribute__((ext_vector_type(8))) short short8;
typedef __attribute__((ext_vector_type(4))) float f32x4;

__device__ __forceinline__ float4 ld4(const float* p) {
    return *reinterpret_cast<const float4*>(p);
}
__device__ __forceinline__ float sigmoidf_(float x) { return 1.f / (1.f + expf(-x)); }
__device__ __forceinline__ u16 f2bf(float x) {
    union { float f; unsigned int u; } v; v.f = x;
    unsigned int r = v.u + 0x7FFFu + ((v.u >> 16) & 1u);
    return (u16)(r >> 16);
}
__device__ __forceinline__ unsigned pk2(float a, float b) {
    float2 t; t.x = a; t.y = b;
    __hip_bfloat162 h = __float22bfloat162_rn(t);
    return *reinterpret_cast<unsigned*>(&h);
}
// merge two (value desc, index asc)-ordered top-2 pairs
__device__ __forceinline__ void merge_top2(float& v1, int& i1, float& v2, int& i2,
                                           float ov1, int oi1, float ov2, int oi2)
{
    if (ov1 > v1 || (ov1 == v1 && oi1 < i1)) {
        float tv = v1; int ti = i1;
        v1 = ov1; i1 = oi1;
        if (ov2 > tv || (ov2 == tv && oi2 < ti)) { v2 = ov2; i2 = oi2; }
        else                                     { v2 = tv;  i2 = ti;  }
    } else {
        if (ov1 > v2 || (ov1 == v2 && oi1 < i2)) { v2 = ov1; i2 = oi1; }
    }
}

// ---------------------------------------------------------------------------
// fp32 tiled GEMM (kept for the one-shot gctx GEMM):
// ---------------------------------------------------------------------------
template<int BM, int BN, int TM, int TN, int AMODE, int BGATHER, int BIASM>
__launch_bounds__(256)
__global__ void gemm_nt(const float* __restrict__ Ap,
                        const int*   __restrict__ ids,
                        const float* __restrict__ Ex,
                        const float* __restrict__ Bp, int ldb, int bofs,
                        const float* __restrict__ bias,
                        const float* __restrict__ addsrc,
                        float* __restrict__ Cp, int ldc,
                        int lda, int K, int s_base, int sdir)
{
    constexpr int BK = 32;
    __shared__ float As[BK][BM + 4];
    __shared__ float Bs[BK][BN + 4];
    const int t  = threadIdx.x;
    const int tx = t & 15, ty = t >> 4;
    const int m_base = blockIdx.y * BM;
    const int n_base = blockIdx.x * BN;

    float acc[TM][TN];
#pragma unroll
    for (int i = 0; i < TM; ++i)
#pragma unroll
        for (int j = 0; j < TN; ++j) acc[i][j] = 0.f;

    constexpr int A_PER = BM * BK / 4 / 256;
    constexpr int B_PER = BN * BK / 4 / 256;

    for (int k0 = 0; k0 < K; k0 += BK) {
#pragma unroll
        for (int j = 0; j < A_PER; ++j) {
            int f   = t + j * 256;
            int row = f >> 3;
            int kk  = (f & 7) << 2;
            int m   = m_base + row;
            float4 v;
            if constexpr (AMODE == 0) {
                v = ld4(Ap + (size_t)m * lda + k0 + kk);
            } else if constexpr (AMODE == 3) {
                int id = ids[m];
                v = ld4(Ex + (size_t)id * EMB_ + k0 + kk);
            } else {  // AMODE == 2
                int k = k0 + kk;
                if (k < HID_) v = ld4(Ap + (size_t)m * HID_ + k);
                else          v = ld4(Ex + (size_t)m * CTX_ + (k - HID_));
            }
            As[kk + 0][row] = v.x; As[kk + 1][row] = v.y;
            As[kk + 2][row] = v.z; As[kk + 3][row] = v.w;
        }
#pragma unroll
        for (int j = 0; j < B_PER; ++j) {
            int f   = t + j * 256;
            int row = f >> 3;
            int kk  = (f & 7) << 2;
            float4 v;
            if constexpr (BGATHER == 1) {
                int n = n_base + row;
                int s = n >> 8, b = n & 255;
                int id = ids[b * S_ + s_base + sdir * s];
                v = ld4(Ex + (size_t)id * EMB_ + k0 + kk);
            } else {
                v = ld4(Bp + (size_t)(n_base + row) * ldb + bofs + k0 + kk);
            }
            Bs[kk + 0][row] = v.x; Bs[kk + 1][row] = v.y;
            Bs[kk + 2][row] = v.z; Bs[kk + 3][row] = v.w;
        }
        __syncthreads();
#pragma unroll
        for (int kk = 0; kk < BK; ++kk) {
            float a[TM], b[TN];
            *(float4*)&a[0] = ld4(&As[kk][ty * TM]);
            if constexpr (TM == 8) *(float4*)&a[4] = ld4(&As[kk][ty * TM + 4]);
            *(float4*)&b[0] = ld4(&Bs[kk][tx * TN]);
            if constexpr (TN == 8) *(float4*)&b[4] = ld4(&Bs[kk][tx * TN + 4]);
#pragma unroll
            for (int i = 0; i < TM; ++i)
#pragma unroll
                for (int j = 0; j < TN; ++j) acc[i][j] += a[i] * b[j];
        }
        __syncthreads();
    }
#pragma unroll
    for (int i = 0; i < TM; ++i) {
        int m = m_base + ty * TM + i;
#pragma unroll
        for (int j = 0; j < TN; ++j) {
            int n = n_base + tx * TN + j;
            float v = acc[i][j];
            if (bias) v += BIASM ? bias[m] : bias[n];
            if (addsrc) v += addsrc[(size_t)m * ldc + n];
            Cp[(size_t)m * ldc + n] = v;
        }
    }
}

// ---------------------------------------------------------------------------
// whh split-transpose: whhA[k][u] = (w_r[u][k], w_z[u][k]) float2;
//                      whhB[k][u] = w_n[u][k].  One-time, per dir.
// ---------------------------------------------------------------------------
__global__ void whh_trans(const float* __restrict__ whh_f, const float* __restrict__ whh_b,
                          float* __restrict__ whhA_f, float* __restrict__ whhB_f,
                          float* __restrict__ whhA_b, float* __restrict__ whhB_b)
{
    int idx = blockIdx.x * 256 + threadIdx.x;        // [0, 524288)
    const float* src = blockIdx.y ? whh_b : whh_f;
    float* dA = blockIdx.y ? whhA_b : whhA_f;
    float* dB = blockIdx.y ? whhB_b : whhB_f;
    if (idx < 262144) {
        int k = idx >> 9, u = idx & 511;
        float2 v;
        v.x = src[(size_t)u * 512 + k];
        v.y = src[(size_t)(512 + u) * 512 + k];
        *(float2*)&dA[(size_t)idx * 2] = v;
    } else {
        int j = idx - 262144;
        int k = j >> 9, u = j & 511;
        dB[j] = src[(size_t)(1024 + u) * 512 + k];
    }
}

// ---------------------------------------------------------------------------
// wout -> bf16 partial precompute.  pk2 == the logits kernel's on-the-fly
// conversion -> bit-identical MFMA inputs either way.
// ---------------------------------------------------------------------------
__global__ void wbf_conv(const float* __restrict__ wout, unsigned* __restrict__ wbf, int npairs)
{
    int idx = blockIdx.x * 256 + threadIdx.x;
    if (idx >= npairs) return;
    float2 v = *reinterpret_cast<const float2*>(wout + (size_t)idx * 2);
    wbf[idx] = pk2(v.x, v.y);
}

// ---------------------------------------------------------------------------
// Fused encoder super-kernel, CU-partitioned grid = 768 (r6 structure).
// rec (128 blocks): 1 unit/thread; weight loads now b64 (r,z pair) + b32 (n)
// -- 2 VMEM issues per k instead of 3, same 3 MB/dir footprint.
// gx (384 blocks): next chunk's input GEMM (unchanged).
// ---------------------------------------------------------------------------
union EncSM {
    struct { float hbuf[2][512][4]; } rec;            // 16 KB
    struct { float As[32][132]; float Bs[32][132]; } gx;   // 33.8 KB
};

__launch_bounds__(512)
__global__ void enc_fused(const float* __restrict__ grec_f, const float* __restrict__ grec_b,
                          float* __restrict__ gout_f, float* __restrict__ gout_b,
                          const float* __restrict__ whhA_f, const float* __restrict__ whhB_f,
                          const float* __restrict__ whhA_b, const float* __restrict__ whhB_b,
                          const float* __restrict__ bhh_f, const float* __restrict__ bhh_b,
                          const float* __restrict__ wih_f, const float* __restrict__ wih_b,
                          const float* __restrict__ bih_f, const float* __restrict__ bih_b,
                          const int* __restrict__ ids, const float* __restrict__ emb,
                          float* __restrict__ hT, int do_rec, int gx_chunk, int nsteps)
{
    __shared__ __align__(16) EncSM sm;
    const int t = threadIdx.x;
    const int idx = blockIdx.x;
    const int grp = idx & 15;

    if (grp >= 8) {
        // ---------------- gx GEMM path ----------------
        if (gx_chunk < 0) return;
        const int g = (idx >> 4) * 8 + (grp - 8);     // [0,384)
        const int dz  = g >= 192;
        const int t192 = dz ? g - 192 : g;
        const int m_base = (t192 & 15) * 128;         // M = 2048
        const int n_base = (t192 >> 4) * 128;         // N = 1536
        const float* W    = dz ? wih_b : wih_f;
        const float* bias = dz ? bih_b : bih_f;
        float*       Cp   = dz ? gout_b : gout_f;
        const int s_base  = dz ? (127 - 8 * gx_chunk) : (8 * gx_chunk);
        const int sdir    = dz ? -1 : 1;
        const int tx = t & 31, ty = t >> 5;           // 32 x 16

        float acc[8][4];
#pragma unroll
        for (int i = 0; i < 8; ++i)
#pragma unroll
            for (int j = 0; j < 4; ++j) acc[i][j] = 0.f;

        for (int k0 = 0; k0 < 512; k0 += 32) {
#pragma unroll
            for (int j = 0; j < 2; ++j) {
                int f   = t + j * 512;
                int row = f >> 3;
                int kk  = (f & 7) << 2;
                int m   = m_base + row;
                int s   = m >> 8, b = m & 255;
                int id  = ids[b * S_ + s_base + sdir * s];
                float4 v = ld4(emb + (size_t)id * EMB_ + k0 + kk);
                sm.gx.As[kk + 0][row] = v.x; sm.gx.As[kk + 1][row] = v.y;
                sm.gx.As[kk + 2][row] = v.z; sm.gx.As[kk + 3][row] = v.w;
                float4 wv = ld4(W + (size_t)(n_base + row) * 512 + k0 + kk);
                sm.gx.Bs[kk + 0][row] = wv.x; sm.gx.Bs[kk + 1][row] = wv.y;
                sm.gx.Bs[kk + 2][row] = wv.z; sm.gx.Bs[kk + 3][row] = wv.w;
            }
            __syncthreads();
#pragma unroll
            for (int kk = 0; kk < 32; ++kk) {
                float a[8], b[4];
                *(float4*)&a[0] = ld4(&sm.gx.As[kk][ty * 8]);
                *(float4*)&a[4] = ld4(&sm.gx.As[kk][ty * 8 + 4]);
                *(float4*)&b[0] = ld4(&sm.gx.Bs[kk][tx * 4]);
#pragma unroll
                for (int i = 0; i < 8; ++i)
#pragma unroll
                    for (int j = 0; j < 4; ++j) acc[i][j] += a[i] * b[j];
            }
            __syncthreads();
        }
#pragma unroll
        for (int i = 0; i < 8; ++i) {
            int m = m_base + ty * 8 + i;
#pragma unroll
            for (int j = 0; j < 4; ++j) {
                int n = n_base + tx * 4 + j;
                Cp[(size_t)m * 1536 + n] = acc[i][j] + bias[n];
            }
        }
        return;
    }

    // ---------------- recurrence path ----------------
    if (idx >= 256 || !do_rec) return;
    const int xcd = idx & 7;
    const int dir = xcd >> 2;
    const int local = (idx >> 4) * 4 + (xcd & 3);     // [0,64)
    const int r0 = local * 4;
    const float* gx  = dir ? grec_b : grec_f;
    const float2* wA = (const float2*)(dir ? whhA_b : whhA_f);
    const float*  wB = dir ? whhB_b : whhB_f;
    const float* bhh = dir ? bhh_b : bhh_f;
    float* hTd = hT + (size_t)dir * (256 * 512);

    const int u = t;                                  // unit = thread

#pragma unroll
    for (int r = 0; r < 4; ++r)
        sm.rec.hbuf[0][u][r] = hTd[(size_t)(r0 + r) * 512 + u];
    const float bh0 = bhh[u], bh1 = bhh[512 + u], bh2 = bhh[1024 + u];
    __syncthreads();

    for (int st = 0; st < nsteps; ++st) {
        const int cur = st & 1, nxt = cur ^ 1;

        // issue gate-input loads EARLY: latency hides under the 512-iter k-loop
        float gx0[4], gx1[4], gx2[4];
#pragma unroll
        for (int r = 0; r < 4; ++r) {
            size_t base = (size_t)((st << 8) + r0 + r) * 1536 + u;
            gx0[r] = gx[base];
            gx1[r] = gx[base + 512];
            gx2[r] = gx[base + 1024];
        }

        float acc0[4] = {0.f,0.f,0.f,0.f};
        float acc1[4] = {0.f,0.f,0.f,0.f};
        float acc2[4] = {0.f,0.f,0.f,0.f};
        const float2* wpA = wA + u;
        const float*  wpB = wB + u;
#pragma unroll 8
        for (int kk = 0; kk < 512; ++kk) {
            float4 hv = *(const float4*)&sm.rec.hbuf[cur][kk][0];
            float2 wrz = wpA[0];
            float  wn  = wpB[0];
            const float* hvp = (const float*)&hv;
#pragma unroll
            for (int r = 0; r < 4; ++r) {
                acc0[r] += wrz.x * hvp[r];
                acc1[r] += wrz.y * hvp[r];
                acc2[r] += wn    * hvp[r];
            }
            wpA += 512; wpB += 512;
        }

#pragma unroll
        for (int r = 0; r < 4; ++r) {
            float hold = sm.rec.hbuf[cur][u][r];
            float rg = sigmoidf_(gx0[r] + acc0[r] + bh0);
            float zg = sigmoidf_(gx1[r] + acc1[r] + bh1);
            float ng = tanhf(gx2[r] + rg * (acc2[r] + bh2));
            sm.rec.hbuf[nxt][u][r] = (1.f - zg) * ng + zg * hold;
        }
        __syncthreads();
    }

    const int lb = nsteps & 1;
#pragma unroll
    for (int r = 0; r < 4; ++r)
        hTd[(size_t)(r0 + r) * 512 + u] = sm.rec.hbuf[lb][u][r];
}

// ---------------------------------------------------------------------------
__global__ void zerof(float* __restrict__ p, int n)
{
    int i = blockIdx.x * 256 + threadIdx.x;
    if (i < n) p[i] = 0.f;
}

__global__ void init_dec(float* __restrict__ hdec, u16* __restrict__ hbf, int* __restrict__ prev)
{
    int i = blockIdx.x * 256 + threadIdx.x;   // 262144
    hdec[i] = 0.f; hbf[i] = 0;
    if (i < B_) prev[i] = SOS_;
}

// hcat (torch h_n.view quirk): hcat[b][k] = h_dir(b>>7)[(2b)&255 + (k>>9)][k&511]
__global__ void hcat_build(const float* __restrict__ hT, float* __restrict__ hcat)
{
    int idx = blockIdx.x * 256 + threadIdx.x; // 262144
    int b = idx >> 10, k = idx & 1023;
    int d = b >> 7;
    int rr = ((2 * b) & 255) + (k >> 9);
    int kk = k & 511;
    hcat[idx] = hT[(size_t)d * 131072 + (size_t)rr * 512 + kk];
}

// ---------------------------------------------------------------------------
// Prologue-only: gh + gi in one launch (round-5 dec_gemm2, unchanged math).
// ---------------------------------------------------------------------------
__launch_bounds__(256)
__global__ void dec_gemm2(const float* __restrict__ hdec, const int* __restrict__ prev,
                          const float* __restrict__ emb,
                          const float* __restrict__ dwhh, const float* __restrict__ dwih,
                          const float* __restrict__ dbhh, const float* __restrict__ gctx,
                          float* __restrict__ ghbuf, float* __restrict__ gibuf)
{
    constexpr int BK = 32;
    __shared__ float As[BK][68];
    __shared__ float Bs[BK][68];
    const int t  = threadIdx.x;
    const int tx = t & 15, ty = t >> 4;
    const bool isH = blockIdx.y < 4;
    const int m_base = (isH ? blockIdx.y : (blockIdx.y - 4)) * 64;
    const int n_base = blockIdx.x * 64;
    const int K   = isH ? 1024 : 512;
    const float* Bp = isH ? dwhh : dwih;
    const int ldb  = isH ? 1024 : 1600;
    float* Cp = isH ? ghbuf : gibuf;

    float acc[4][4];
#pragma unroll
    for (int i = 0; i < 4; ++i)
#pragma unroll
        for (int j = 0; j < 4; ++j) acc[i][j] = 0.f;

    for (int k0 = 0; k0 < K; k0 += BK) {
#pragma unroll
        for (int j = 0; j < 2; ++j) {
            int f   = t + j * 256;
            int row = f >> 3;
            int kk  = (f & 7) << 2;
            int m   = m_base + row;
            float4 v;
            if (isH) v = ld4(hdec + (size_t)m * HID_ + k0 + kk);
            else     v = ld4(emb + (size_t)prev[m] * EMB_ + k0 + kk);
            As[kk + 0][row] = v.x; As[kk + 1][row] = v.y;
            As[kk + 2][row] = v.z; As[kk + 3][row] = v.w;
            float4 w = ld4(Bp + (size_t)(n_base + row) * ldb + k0 + kk);
            Bs[kk + 0][row] = w.x; Bs[kk + 1][row] = w.y;
            Bs[kk + 2][row] = w.z; Bs[kk + 3][row] = w.w;
        }
        __syncthreads();
#pragma unroll
        for (int kk = 0; kk < BK; ++kk) {
            float a[4], b[4];
            *(float4*)&a[0] = ld4(&As[kk][ty * 4]);
            *(float4*)&b[0] = ld4(&Bs[kk][tx * 4]);
#pragma unroll
            for (int i = 0; i < 4; ++i)
#pragma unroll
                for (int j = 0; j < 4; ++j) acc[i][j] += a[i] * b[j];
        }
        __syncthreads();
    }
#pragma unroll
    for (int i = 0; i < 4; ++i) {
        int m = m_base + ty * 4 + i;
#pragma unroll
        for (int j = 0; j < 4; ++j) {
            int n = n_base + tx * 4 + j;
            float v = acc[i][j];
            if (isH) v += dbhh[n];
            else     v += gctx[(size_t)m * 3072 + n];
            Cp[(size_t)m * 3072 + n] = v;
        }
    }
}

// ---------------------------------------------------------------------------
// gi-only GEMM (steady-state decoder): identical math to dec_gemm2's gi path.
// grid (48, 4), 256 thr.
// ---------------------------------------------------------------------------
__launch_bounds__(256)
__global__ void dec_gi(const int* __restrict__ prev, const float* __restrict__ emb,
                       const float* __restrict__ dwih, const float* __restrict__ gctx,
                       float* __restrict__ gibuf)
{
    constexpr int BK = 32;
    __shared__ float As[BK][68];
    __shared__ float Bs[BK][68];
    const int t  = threadIdx.x;
    const int tx = t & 15, ty = t >> 4;
    const int m_base = blockIdx.y * 64;
    const int n_base = blockIdx.x * 64;

    float acc[4][4];
#pragma unroll
    for (int i = 0; i < 4; ++i)
#pragma unroll
        for (int j = 0; j < 4; ++j) acc[i][j] = 0.f;

    for (int k0 = 0; k0 < 512; k0 += BK) {
#pragma unroll
        for (int j = 0; j < 2; ++j) {
            int f   = t + j * 256;
            int row = f >> 3;
            int kk  = (f & 7) << 2;
            int m   = m_base + row;
            float4 v = ld4(emb + (size_t)prev[m] * EMB_ + k0 + kk);
            As[kk + 0][row] = v.x; As[kk + 1][row] = v.y;
            As[kk + 2][row] = v.z; As[kk + 3][row] = v.w;
            float4 w = ld4(dwih + (size_t)(n_base + row) * 1600 + k0 + kk);
            Bs[kk + 0][row] = w.x; Bs[kk + 1][row] = w.y;
            Bs[kk + 2][row] = w.z; Bs[kk + 3][row] = w.w;
        }
        __syncthreads();
#pragma unroll
        for (int kk = 0; kk < BK; ++kk) {
            float a[4], b[4];
            *(float4*)&a[0] = ld4(&As[kk][ty * 4]);
            *(float4*)&b[0] = ld4(&Bs[kk][tx * 4]);
#pragma unroll
            for (int i = 0; i < 4; ++i)
#pragma unroll
                for (int j = 0; j < 4; ++j) acc[i][j] += a[i] * b[j];
        }
        __syncthreads();
    }
#pragma unroll
    for (int i = 0; i < 4; ++i) {
        int m = m_base + ty * 4 + i;
#pragma unroll
        for (int j = 0; j < 4; ++j) {
            int n = n_base + tx * 4 + j;
            gibuf[(size_t)m * 3072 + n] = acc[i][j] + gctx[(size_t)m * 3072 + n];
        }
    }
}

__global__ void dec_combine(const float* __restrict__ gi, const float* __restrict__ gh,
                            float* __restrict__ hdec, u16* __restrict__ hbf)
{
    int idx = blockIdx.x * 256 + threadIdx.x;  // 262144
    int b = idx >> 10, u = idx & 1023;
    size_t gb = (size_t)b * 3072;
    float r = sigmoidf_(gi[gb + u]            + gh[gb + u]);
    float z = sigmoidf_(gi[gb + HID_ + u]     + gh[gb + HID_ + u]);
    float n = tanhf    (gi[gb + 2 * HID_ + u] + r * gh[gb + 2 * HID_ + u]);
    float v = (1.f - z) * n + z * hdec[idx];
    hdec[idx] = v;
    hbf[idx] = f2bf(v);
}

// ---------------------------------------------------------------------------
// Fused launch: y==0 -> bf16 MFMA logits + softmax/top2 partials (250 blocks);
// y==1 -> NEXT step's gh GEMM (192 blocks; hdec(t+1) is ready before logits).
// gh VALU work rides under logits' MFMA on co-resident CUs.
// Wbf covers rows [0, wbfRows) with pk2-identical bf16; rest converts inline.
// ---------------------------------------------------------------------------
union DecSM {
    struct { u16 As[256][72]; u16 Bs[128][72]; } lg;   // 55.3 KB
    struct { float As[32][68]; float Bs[32][68]; } gh; // 17.4 KB
};

__launch_bounds__(512)
__global__ void dec_lh(const u16* __restrict__ A, const float* __restrict__ Wf,
                       const u16* __restrict__ Wbf, int wbfRows,
                       const float* __restrict__ bias,
                       float* __restrict__ pmax, float* __restrict__ psum,
                       float* __restrict__ ptv, int* __restrict__ pti,
                       const float* __restrict__ hdec, const float* __restrict__ dwhh,
                       const float* __restrict__ dbhh, float* __restrict__ ghbuf,
                       int doGh)
{
    __shared__ __align__(16) DecSM sm;
    const int t = threadIdx.x;

    if (blockIdx.y == 1) {
        // ---------------- gh GEMM for step t+1 ----------------
        if (!doGh || blockIdx.x >= 192) return;
        const int g  = blockIdx.x;
        const int m0 = (g / 48) * 64;
        const int n0 = (g % 48) * 64;
        const int tx = t & 15, ty = t >> 4;           // ty in [0,32)

        float acc[2][4];
#pragma unroll
        for (int i = 0; i < 2; ++i)
#pragma unroll
            for (int j = 0; j < 4; ++j) acc[i][j] = 0.f;

        for (int k0 = 0; k0 < 1024; k0 += 32) {
            {
                int row = t >> 3;
                int kk  = (t & 7) << 2;
                float4 v = ld4(hdec + (size_t)(m0 + row) * HID_ + k0 + kk);
                sm.gh.As[kk + 0][row] = v.x; sm.gh.As[kk + 1][row] = v.y;
                sm.gh.As[kk + 2][row] = v.z; sm.gh.As[kk + 3][row] = v.w;
                float4 w = ld4(dwhh + (size_t)(n0 + row) * 1024 + k0 + kk);
                sm.gh.Bs[kk + 0][row] = w.x; sm.gh.Bs[kk + 1][row] = w.y;
                sm.gh.Bs[kk + 2][row] = w.z; sm.gh.Bs[kk + 3][row] = w.w;
            }
            __syncthreads();
#pragma unroll
            for (int kk = 0; kk < 32; ++kk) {
                float2 a = *(const float2*)&sm.gh.As[kk][ty * 2];
                float b[4];
                *(float4*)&b[0] = ld4(&sm.gh.Bs[kk][tx * 4]);
#pragma unroll
                for (int j = 0; j < 4; ++j) {
                    acc[0][j] += a.x * b[j];
                    acc[1][j] += a.y * b[j];
                }
            }
            __syncthreads();
        }
#pragma unroll
        for (int i = 0; i < 2; ++i) {
            int m = m0 + ty * 2 + i;
#pragma unroll
            for (int j = 0; j < 4; ++j) {
                int n = n0 + tx * 4 + j;
                ghbuf[(size_t)m * 3072 + n] = acc[i][j] + dbhh[n];
            }
        }
        return;
    }

    // ---------------- logits path ----------------
    const int lane = t & 63, wave = t >> 6;
    const int wm = (wave & 3) * 64, wn = (wave >> 2) * 64;
    const int n0 = blockIdx.x * 128;
    f32x4 acc[4][4];
#pragma unroll
    for (int i = 0; i < 4; ++i)
#pragma unroll
        for (int j = 0; j < 4; ++j) acc[i][j] = (f32x4){0.f, 0.f, 0.f, 0.f};
    const int arow = t >> 1, aoff = (t & 1) * 32;
    const int brow = t >> 2, boff = (t & 3) * 16;
    const bool useBf = (n0 + brow) < wbfRows;

    for (int k0 = 0; k0 < 1024; k0 += 64) {
#pragma unroll
        for (int q = 0; q < 4; ++q) {
            *(uint4*)&sm.lg.As[arow][aoff + q * 8] =
                *(const uint4*)(A + (size_t)arow * 1024 + k0 + aoff + q * 8);
        }
        if (useBf) {
            const u16* wr = Wbf + (size_t)(n0 + brow) * 1024 + k0 + boff;
            *(uint4*)&sm.lg.Bs[brow][boff]     = *(const uint4*)(wr);
            *(uint4*)&sm.lg.Bs[brow][boff + 8] = *(const uint4*)(wr + 8);
        } else {
            const float* wr = Wf + (size_t)(n0 + brow) * 1024 + k0 + boff;
#pragma unroll
            for (int q = 0; q < 2; ++q) {
                float4 x = ld4(wr + q * 8);
                float4 y = ld4(wr + q * 8 + 4);
                uint4 o;
                o.x = pk2(x.x, x.y); o.y = pk2(x.z, x.w);
                o.z = pk2(y.x, y.y); o.w = pk2(y.z, y.w);
                *(uint4*)&sm.lg.Bs[brow][boff + q * 8] = o;
            }
        }
        __syncthreads();
#pragma unroll
        for (int s = 0; s < 2; ++s) {
            short8 a[4], b[4];
            int j0 = s * 32 + (lane >> 4) * 8;
#pragma unroll
            for (int i = 0; i < 4; ++i) {
                a[i] = *(const short8*)&sm.lg.As[wm + i * 16 + (lane & 15)][j0];
                b[i] = *(const short8*)&sm.lg.Bs[wn + i * 16 + (lane & 15)][j0];
            }
#pragma unroll
            for (int i = 0; i < 4; ++i)
#pragma unroll
                for (int j = 0; j < 4; ++j)
                    acc[i][j] = __builtin_amdgcn_mfma_f32_16x16x32_bf16(a[i], b[j], acc[i][j], 0, 0, 0);
        }
        __syncthreads();
    }

    // ---- fused epilogue: per-row (max, sumexp, top2) over this wave's 64 cols
    const int htile = blockIdx.x * 2 + (wn >> 6);
    float bn[4]; int jx[4];
#pragma unroll
    for (int j = 0; j < 4; ++j) { jx[j] = n0 + wn + j * 16 + (lane & 15); bn[j] = bias[jx[j]]; }
#pragma unroll
    for (int i = 0; i < 4; ++i) {
#pragma unroll
        for (int rr = 0; rr < 4; ++rr) {
            float v[4];
#pragma unroll
            for (int j = 0; j < 4; ++j) v[j] = acc[i][j][rr] + bn[j];
            float v1 = v[0], v2 = -3.4e38f; int i1 = jx[0], i2 = 0x7fffffff;
#pragma unroll
            for (int j = 1; j < 4; ++j) {
                if (v[j] > v1)      { v2 = v1; i2 = i1; v1 = v[j]; i1 = jx[j]; }
                else if (v[j] > v2) { v2 = v[j]; i2 = jx[j]; }
            }
#pragma unroll
            for (int mask = 1; mask <= 8; mask <<= 1) {
                float ov1 = __shfl_xor(v1, mask), ov2 = __shfl_xor(v2, mask);
                int   oi1 = __shfl_xor(i1, mask), oi2 = __shfl_xor(i2, mask);
                merge_top2(v1, i1, v2, i2, ov1, oi1, ov2, oi2);
            }
            float rmax = v1;
            float s = 0.f;
#pragma unroll
            for (int j = 0; j < 4; ++j) s += expf(v[j] - rmax);
#pragma unroll
            for (int mask = 1; mask <= 8; mask <<= 1) s += __shfl_xor(s, mask);
            if ((lane & 15) == 0) {
                int row = wm + i * 16 + (lane >> 4) * 4 + rr;
                size_t base = (size_t)row * 500 + htile;
                pmax[base] = rmax; psum[base] = s;
                ptv[base * 2] = v1; ptv[base * 2 + 1] = v2;
                pti[base * 2] = i1; pti[base * 2 + 1] = i2;
            }
        }
    }
}

// ---------------------------------------------------------------------------
// Per-row combine of 500 half-tile partials (unchanged).
// ---------------------------------------------------------------------------
__launch_bounds__(256)
__global__ void dec_reduce(const float* __restrict__ pmax, const float* __restrict__ psum,
                           const float* __restrict__ ptv, const int* __restrict__ pti,
                           const float* __restrict__ hdec, const float* __restrict__ wout,
                           const float* __restrict__ bout,
                           float* __restrict__ out, int* __restrict__ prev, int tstep)
{
    __shared__ float sv[256]; __shared__ int sti[256]; __shared__ int ssl[256];
    __shared__ float cvv[1000]; __shared__ int cii[1000];
    __shared__ float c8v[8]; __shared__ int c8i[8]; __shared__ float c8e[8];
    const int b = blockIdx.x, tid = threadIdx.x;
    const float* pm = pmax + (size_t)b * 500;
    const float* ps = psum + (size_t)b * 500;

    float m = -3.4e38f;
    for (int i = tid; i < 500; i += 256) m = fmaxf(m, pm[i]);
    sv[tid] = m; __syncthreads();
    for (int off = 128; off; off >>= 1) { if (tid < off) sv[tid] = fmaxf(sv[tid], sv[tid + off]); __syncthreads(); }
    float gmax = sv[0]; __syncthreads();

    float s = 0.f;
    for (int i = tid; i < 500; i += 256) s += ps[i] * expf(pm[i] - gmax);
    sv[tid] = s; __syncthreads();
    for (int off = 128; off; off >>= 1) { if (tid < off) sv[tid] += sv[tid + off]; __syncthreads(); }
    float gsum = sv[0]; __syncthreads();

    for (int i = tid; i < 1000; i += 256) { cvv[i] = ptv[(size_t)b * 1000 + i]; cii[i] = pti[(size_t)b * 1000 + i]; }
    __syncthreads();

    for (int c = 0; c < 8; ++c) {
        float bv = -3.4e38f; int bi = 0x7fffffff, bs = 0;
        for (int i = tid; i < 1000; i += 256) {
            float v = cvv[i]; int ix = cii[i];
            if (v > bv || (v == bv && ix < bi)) { bv = v; bi = ix; bs = i; }
        }
        sv[tid] = bv; sti[tid] = bi; ssl[tid] = bs; __syncthreads();
        for (int off = 128; off; off >>= 1) {
            if (tid < off) {
                if (sv[tid + off] > sv[tid] ||
                    (sv[tid + off] == sv[tid] && sti[tid + off] < sti[tid])) {
                    sv[tid] = sv[tid + off]; sti[tid] = sti[tid + off]; ssl[tid] = ssl[tid + off];
                }
            }
            __syncthreads();
        }
        if (tid == 0) { c8v[c] = sv[0]; c8i[c] = sti[0]; cvv[ssl[0]] = -3.4e38f; }
        __syncthreads();
    }

    {   // exact fp32 rescore, 2 candidates per wave
        int lane = tid & 63, wv = tid >> 6;
        const float* hr = hdec + (size_t)b * HID_;
        for (int c = wv; c < 8; c += 4) {
            const float* wr = wout + (size_t)c8i[c] * HID_;
            float a = 0.f;
            for (int k = lane * 4; k < HID_; k += 256) {
                float4 x = ld4(hr + k), y = ld4(wr + k);
                a += x.x * y.x + x.y * y.y + x.z * y.z + x.w * y.w;
            }
#pragma unroll
            for (int off = 32; off; off >>= 1) a += __shfl_down(a, off);
            if (lane == 0) c8e[c] = a + bout[c8i[c]];
        }
    }
    __syncthreads();

    if (tid == 0) {
        float bv = c8e[0]; int bi = c8i[0]; float av = c8v[0];
        for (int c = 1; c < 8; ++c)
            if (c8e[c] > bv || (c8e[c] == bv && c8i[c] < bi)) { bv = c8e[c]; bi = c8i[c]; av = c8v[c]; }
        float p = expf(av - gmax) / gsum;
        float lp = logf(p + 1e-12f);
        out[(size_t)b * TMAX_ + tstep] = (float)bi;
        out[B_ * TMAX_ + (size_t)b * TMAX_ + tstep] = lp;
        prev[b] = bi;
    }
}

// ---------------------------------------------------------------------------
extern "C" void kernel_launch(void* const* d_in, const int* in_sizes, int n_in,
                              void* d_out, int out_size, void* d_ws, size_t ws_size,
                              hipStream_t stream)
{
    const int*   ids   = (const int*)  d_in[0];
    const float* cvec  = (const float*)d_in[1];
    const float* emb   = (const float*)d_in[2];
    const float* wih_f = (const float*)d_in[3];
    const float* whh_f = (const float*)d_in[4];
    const float* bih_f = (const float*)d_in[5];
    const float* bhh_f = (const float*)d_in[6];
    const float* wih_b = (const float*)d_in[7];
    const float* whh_b = (const float*)d_in[8];
    const float* bih_b = (const float*)d_in[9];
    const float* bhh_b = (const float*)d_in[10];
    const float* dwih  = (const float*)d_in[11];
    const float* dwhh  = (const float*)d_in[12];
    const float* dbih  = (const float*)d_in[13];
    const float* dbhh  = (const float*)d_in[14];
    const float* wout  = (const float*)d_in[15];
    const float* bout  = (const float*)d_in[16];
    float* out = (float*)d_out;

    // workspace carve (floats); base total = 15,859,968 f = 63.4 MB.
    float* w      = (float*)d_ws;
    float* buf0_f = w;                          // 3,145,728
    float* buf0_b = w + 3145728;                // 3,145,728
    float* buf1_f = w + 6291456;                // 3,145,728
    float* buf1_b = w + 9437184;                // 3,145,728
    float* hT     = w + 12582912;               // 262,144  [dir][row][unit]
    float* hcat   = w + 12845056;               // 262,144
    float* hdec   = w + 13107200;               // 262,144  LIVE decode
    float* gctx   = w + 13369344;               // 786,432  LIVE decode
    u16*   hdecb  = (u16*)(w + 14155776);       // 131,072 f LIVE decode
    int*   prev   = (int*)(w + 14286848);       // 256       LIVE decode
    float* whhA_f = w + 14287104;               // 524,288
    float* whhB_f = w + 14811392;               // 262,144
    float* whhA_b = w + 15073536;               // 524,288
    float* whhB_b = w + 15597824;               // 262,144 -> end 15,859,968
    u16*   wbf_big = (u16*)(w + 15859968);      // optional: 32,768,000 u16
    const int big_ws = (ws_size >= (size_t)(15859968 + 16384000) * 4);
    // --- decode-phase aliases over the dead region [0, 13,107,200) ---
    float* gibuf  = w;                          // 786,432
    float* ghbuf  = w + 786432;                 // 786,432
    float* pmax   = w + 1572864;                // 128,000
    float* psum   = w + 1700864;                // 128,000
    float* ptv    = w + 1828864;                // 256,000
    int*   pti    = (int*)(w + 2084864);        // 256,000
    u16*   wbf_part = (u16*)(w + 2340864);      // 21,495,808 u16 (10,747,904 f < 10,766,336 avail)
    const int wbfRows = big_ws ? VOC_ : 20992;  // 20992 = 164 * 128 (full n-tiles)
    u16* wbfPtr = big_ws ? wbf_big : wbf_part;

    zerof<<<1024, 256, 0, stream>>>(hT, 262144);
    init_dec<<<1024, 256, 0, stream>>>(hdec, hdecb, prev);
    whh_trans<<<dim3(2048, 2), 256, 0, stream>>>(whh_f, whh_b,
                                                 whhA_f, whhB_f, whhA_b, whhB_b);

    // ---------------- encoder: 16 chunks x 8 steps, CU-partitioned dispatches ------
    enc_fused<<<768, 512, 0, stream>>>(
        buf0_f, buf0_b, buf0_f, buf0_b, whhA_f, whhB_f, whhA_b, whhB_b,
        bhh_f, bhh_b, wih_f, wih_b, bih_f, bih_b, ids, emb, hT, 0, 0, 8);
    for (int c = 1; c < 16; ++c) {
        float* rf = ((c - 1) & 1) ? buf1_f : buf0_f;
        float* rb = ((c - 1) & 1) ? buf1_b : buf0_b;
        float* of = (c & 1) ? buf1_f : buf0_f;
        float* ob = (c & 1) ? buf1_b : buf0_b;
        enc_fused<<<768, 512, 0, stream>>>(
            rf, rb, of, ob, whhA_f, whhB_f, whhA_b, whhB_b,
            bhh_f, bhh_b, wih_f, wih_b, bih_f, bih_b, ids, emb, hT, 1, c, 8);
    }
    enc_fused<<<768, 512, 0, stream>>>(
        buf1_f, buf1_b, buf1_f, buf1_b, whhA_f, whhB_f, whhA_b, whhB_b,
        bhh_f, bhh_b, wih_f, wih_b, bih_f, bih_b, ids, emb, hT, 1, -1, 8);

    hcat_build<<<1024, 256, 0, stream>>>(hT, hcat);

    // bf16 wout precompute (pk2-identical); encoder buffers are dead now
    {
        int npairs = wbfRows * 512;
        wbf_conv<<<(npairs + 255) / 256, 256, 0, stream>>>(wout, (unsigned*)wbfPtr, npairs);
    }

    // gctx[b][3072] = [hcat|cvec] @ dec_wih[:,512:1600]^T + dbih
    gemm_nt<64, 64, 4, 4, 2, 0, 0><<<dim3(48, 4), 256, 0, stream>>>(
        hcat, nullptr, cvec, dwih, 1600, 512, dbih, nullptr,
        gctx, 3072, 1024, 1088, 0, 0);

    // ---------------- decoder: 40 greedy steps ----------------
    // prologue: gh(0)+gi(0) and combine -> h(1), hb(1)
    dec_gemm2<<<dim3(48, 8), 256, 0, stream>>>(
        hdec, prev, emb, dwhh, dwih, dbhh, gctx, ghbuf, gibuf);
    dec_combine<<<1024, 256, 0, stream>>>(gibuf, ghbuf, hdec, hdecb);
    for (int t = 0; t < TMAX_; ++t) {
        // logits(t) over h(t+1)  ||  gh(t+1) over hdec=h(t+1)  (independent)
        dec_lh<<<dim3(250, 2), 512, 0, stream>>>(
            hdecb, wout, wbfPtr, wbfRows, bout,
            pmax, psum, ptv, pti, hdec, dwhh, dbhh, ghbuf, (t < TMAX_ - 1));
        dec_reduce<<<256, 256, 0, stream>>>(pmax, psum, ptv, pti,
                                            hdec, wout, bout, out, prev, t);
        if (t < TMAX_ - 1) {
            dec_gi<<<dim3(48, 4), 256, 0, stream>>>(prev, emb, dwih, gctx, gibuf);
            dec_combine<<<1024, 256, 0, stream>>>(gibuf, ghbuf, hdec, hdecb);
        }
    }
}

// Round 8
// 9546.521 us; speedup vs baseline: 1.3198x; 1.3198x over previous
//
#include <hip/hip_runtime.h>
#include <hip/hip_bf16.h>
#include <math.h>

#define B_    256
#define S_    128
#define EMB_  512
#define H2_   512
#define HID_  1024
#define CTX_  64
#define VOC_  32000
#define TMAX_ 40
#define SOS_  2

typedef unsigned short u16;
typedef __attribute__((ext_vector_type(8))) short short8;
typedef __attribute__((ext_vector_type(4))) float f32x4;

__device__ __forceinline__ float4 ld4(const float* p) {
    return *reinterpret_cast<const float4*>(p);
}
__device__ __forceinline__ float sigmoidf_(float x) { return 1.f / (1.f + expf(-x)); }
__device__ __forceinline__ u16 f2bf(float x) {
    union { float f; unsigned int u; } v; v.f = x;
    unsigned int r = v.u + 0x7FFFu + ((v.u >> 16) & 1u);
    return (u16)(r >> 16);
}
__device__ __forceinline__ unsigned pk2(float a, float b) {
    float2 t; t.x = a; t.y = b;
    __hip_bfloat162 h = __float22bfloat162_rn(t);
    return *reinterpret_cast<unsigned*>(&h);
}
// merge two (value desc, index asc)-ordered top-2 pairs
__device__ __forceinline__ void merge_top2(float& v1, int& i1, float& v2, int& i2,
                                           float ov1, int oi1, float ov2, int oi2)
{
    if (ov1 > v1 || (ov1 == v1 && oi1 < i1)) {
        float tv = v1; int ti = i1;
        v1 = ov1; i1 = oi1;
        if (ov2 > tv || (ov2 == tv && oi2 < ti)) { v2 = ov2; i2 = oi2; }
        else                                     { v2 = tv;  i2 = ti;  }
    } else {
        if (ov1 > v2 || (ov1 == v2 && oi1 < i2)) { v2 = ov1; i2 = oi1; }
    }
}

// ---------------------------------------------------------------------------
// fp32 tiled GEMM (kept for the one-shot gctx GEMM):
// ---------------------------------------------------------------------------
template<int BM, int BN, int TM, int TN, int AMODE, int BGATHER, int BIASM>
__launch_bounds__(256)
__global__ void gemm_nt(const float* __restrict__ Ap,
                        const int*   __restrict__ ids,
                        const float* __restrict__ Ex,
                        const float* __restrict__ Bp, int ldb, int bofs,
                        const float* __restrict__ bias,
                        const float* __restrict__ addsrc,
                        float* __restrict__ Cp, int ldc,
                        int lda, int K, int s_base, int sdir)
{
    constexpr int BK = 32;
    __shared__ float As[BK][BM + 4];
    __shared__ float Bs[BK][BN + 4];
    const int t  = threadIdx.x;
    const int tx = t & 15, ty = t >> 4;
    const int m_base = blockIdx.y * BM;
    const int n_base = blockIdx.x * BN;

    float acc[TM][TN];
#pragma unroll
    for (int i = 0; i < TM; ++i)
#pragma unroll
        for (int j = 0; j < TN; ++j) acc[i][j] = 0.f;

    constexpr int A_PER = BM * BK / 4 / 256;
    constexpr int B_PER = BN * BK / 4 / 256;

    for (int k0 = 0; k0 < K; k0 += BK) {
#pragma unroll
        for (int j = 0; j < A_PER; ++j) {
            int f   = t + j * 256;
            int row = f >> 3;
            int kk  = (f & 7) << 2;
            int m   = m_base + row;
            float4 v;
            if constexpr (AMODE == 0) {
                v = ld4(Ap + (size_t)m * lda + k0 + kk);
            } else if constexpr (AMODE == 3) {
                int id = ids[m];
                v = ld4(Ex + (size_t)id * EMB_ + k0 + kk);
            } else {  // AMODE == 2
                int k = k0 + kk;
                if (k < HID_) v = ld4(Ap + (size_t)m * HID_ + k);
                else          v = ld4(Ex + (size_t)m * CTX_ + (k - HID_));
            }
            As[kk + 0][row] = v.x; As[kk + 1][row] = v.y;
            As[kk + 2][row] = v.z; As[kk + 3][row] = v.w;
        }
#pragma unroll
        for (int j = 0; j < B_PER; ++j) {
            int f   = t + j * 256;
            int row = f >> 3;
            int kk  = (f & 7) << 2;
            float4 v;
            if constexpr (BGATHER == 1) {
                int n = n_base + row;
                int s = n >> 8, b = n & 255;
                int id = ids[b * S_ + s_base + sdir * s];
                v = ld4(Ex + (size_t)id * EMB_ + k0 + kk);
            } else {
                v = ld4(Bp + (size_t)(n_base + row) * ldb + bofs + k0 + kk);
            }
            Bs[kk + 0][row] = v.x; Bs[kk + 1][row] = v.y;
            Bs[kk + 2][row] = v.z; Bs[kk + 3][row] = v.w;
        }
        __syncthreads();
#pragma unroll
        for (int kk = 0; kk < BK; ++kk) {
            float a[TM], b[TN];
            *(float4*)&a[0] = ld4(&As[kk][ty * TM]);
            if constexpr (TM == 8) *(float4*)&a[4] = ld4(&As[kk][ty * TM + 4]);
            *(float4*)&b[0] = ld4(&Bs[kk][tx * TN]);
            if constexpr (TN == 8) *(float4*)&b[4] = ld4(&Bs[kk][tx * TN + 4]);
#pragma unroll
            for (int i = 0; i < TM; ++i)
#pragma unroll
                for (int j = 0; j < TN; ++j) acc[i][j] += a[i] * b[j];
        }
        __syncthreads();
    }
#pragma unroll
    for (int i = 0; i < TM; ++i) {
        int m = m_base + ty * TM + i;
#pragma unroll
        for (int j = 0; j < TN; ++j) {
            int n = n_base + tx * TN + j;
            float v = acc[i][j];
            if (bias) v += BIASM ? bias[m] : bias[n];
            if (addsrc) v += addsrc[(size_t)m * ldc + n];
            Cp[(size_t)m * ldc + n] = v;
        }
    }
}

// ---------------------------------------------------------------------------
// whh transpose: whhU[k][g][u] = whh[g*512+u][k].  One-time, per dir.
// Row stride 6144 B (non-pow2) -- spreads L2 channels.  (r7's pow-2 split
// strides caused channel aliasing: 300 -> 494 us.  Keep non-pow2.)
// ---------------------------------------------------------------------------
__global__ void whh_trans(const float* __restrict__ whh_f, const float* __restrict__ whh_b,
                          float* __restrict__ whhU_f, float* __restrict__ whhU_b)
{
    int idx = blockIdx.x * 256 + threadIdx.x;        // [0, 786432)
    const float* src = blockIdx.y ? whh_b : whh_f;
    float*       dst = blockIdx.y ? whhU_b : whhU_f;
    int k  = idx / 1536;
    int rem = idx - k * 1536;
    int g  = rem >> 9;
    int u  = rem & 511;
    dst[idx] = src[(size_t)(g * 512 + u) * 512 + k];
}

// ---------------------------------------------------------------------------
// wout -> bf16 partial precompute.  pk2 == the logits kernel's on-the-fly
// conversion -> bit-identical MFMA inputs either way.
// ---------------------------------------------------------------------------
__global__ void wbf_conv(const float* __restrict__ wout, unsigned* __restrict__ wbf, int npairs)
{
    int idx = blockIdx.x * 256 + threadIdx.x;
    if (idx >= npairs) return;
    float2 v = *reinterpret_cast<const float2*>(wout + (size_t)idx * 2);
    wbf[idx] = pk2(v.x, v.y);
}

// ---------------------------------------------------------------------------
// Fused encoder super-kernel, CU-partitioned grid = 768 (round-6 proven).
// rec (128 blocks): 1 unit/thread, 3x b32 weight streams from whhU (6144 B
// stride), h in LDS, 1 barrier/step.  gx (384 blocks): next chunk's GEMM.
// ---------------------------------------------------------------------------
union EncSM {
    struct { float hbuf[2][512][4]; } rec;            // 16 KB
    struct { float As[32][132]; float Bs[32][132]; } gx;   // 33.8 KB
};

__launch_bounds__(512)
__global__ void enc_fused(const float* __restrict__ grec_f, const float* __restrict__ grec_b,
                          float* __restrict__ gout_f, float* __restrict__ gout_b,
                          const float* __restrict__ whhU_f, const float* __restrict__ whhU_b,
                          const float* __restrict__ bhh_f, const float* __restrict__ bhh_b,
                          const float* __restrict__ wih_f, const float* __restrict__ wih_b,
                          const float* __restrict__ bih_f, const float* __restrict__ bih_b,
                          const int* __restrict__ ids, const float* __restrict__ emb,
                          float* __restrict__ hT, int do_rec, int gx_chunk, int nsteps)
{
    __shared__ __align__(16) EncSM sm;
    const int t = threadIdx.x;
    const int idx = blockIdx.x;
    const int grp = idx & 15;

    if (grp >= 8) {
        // ---------------- gx GEMM path ----------------
        if (gx_chunk < 0) return;
        const int g = (idx >> 4) * 8 + (grp - 8);     // [0,384)
        const int dz  = g >= 192;
        const int t192 = dz ? g - 192 : g;
        const int m_base = (t192 & 15) * 128;         // M = 2048
        const int n_base = (t192 >> 4) * 128;         // N = 1536
        const float* W    = dz ? wih_b : wih_f;
        const float* bias = dz ? bih_b : bih_f;
        float*       Cp   = dz ? gout_b : gout_f;
        const int s_base  = dz ? (127 - 8 * gx_chunk) : (8 * gx_chunk);
        const int sdir    = dz ? -1 : 1;
        const int tx = t & 31, ty = t >> 5;           // 32 x 16

        float acc[8][4];
#pragma unroll
        for (int i = 0; i < 8; ++i)
#pragma unroll
            for (int j = 0; j < 4; ++j) acc[i][j] = 0.f;

        for (int k0 = 0; k0 < 512; k0 += 32) {
#pragma unroll
            for (int j = 0; j < 2; ++j) {
                int f   = t + j * 512;
                int row = f >> 3;
                int kk  = (f & 7) << 2;
                int m   = m_base + row;
                int s   = m >> 8, b = m & 255;
                int id  = ids[b * S_ + s_base + sdir * s];
                float4 v = ld4(emb + (size_t)id * EMB_ + k0 + kk);
                sm.gx.As[kk + 0][row] = v.x; sm.gx.As[kk + 1][row] = v.y;
                sm.gx.As[kk + 2][row] = v.z; sm.gx.As[kk + 3][row] = v.w;
                float4 wv = ld4(W + (size_t)(n_base + row) * 512 + k0 + kk);
                sm.gx.Bs[kk + 0][row] = wv.x; sm.gx.Bs[kk + 1][row] = wv.y;
                sm.gx.Bs[kk + 2][row] = wv.z; sm.gx.Bs[kk + 3][row] = wv.w;
            }
            __syncthreads();
#pragma unroll
            for (int kk = 0; kk < 32; ++kk) {
                float a[8], b[4];
                *(float4*)&a[0] = ld4(&sm.gx.As[kk][ty * 8]);
                *(float4*)&a[4] = ld4(&sm.gx.As[kk][ty * 8 + 4]);
                *(float4*)&b[0] = ld4(&sm.gx.Bs[kk][tx * 4]);
#pragma unroll
                for (int i = 0; i < 8; ++i)
#pragma unroll
                    for (int j = 0; j < 4; ++j) acc[i][j] += a[i] * b[j];
            }
            __syncthreads();
        }
#pragma unroll
        for (int i = 0; i < 8; ++i) {
            int m = m_base + ty * 8 + i;
#pragma unroll
            for (int j = 0; j < 4; ++j) {
                int n = n_base + tx * 4 + j;
                Cp[(size_t)m * 1536 + n] = acc[i][j] + bias[n];
            }
        }
        return;
    }

    // ---------------- recurrence path ----------------
    if (idx >= 256 || !do_rec) return;
    const int xcd = idx & 7;
    const int dir = xcd >> 2;
    const int local = (idx >> 4) * 4 + (xcd & 3);     // [0,64)
    const int r0 = local * 4;
    const float* gx  = dir ? grec_b : grec_f;
    const float* whx = dir ? whhU_b : whhU_f;
    const float* bhh = dir ? bhh_b : bhh_f;
    float* hTd = hT + (size_t)dir * (256 * 512);

    const int u = t;                                  // unit = thread

#pragma unroll
    for (int r = 0; r < 4; ++r)
        sm.rec.hbuf[0][u][r] = hTd[(size_t)(r0 + r) * 512 + u];
    const float bh0 = bhh[u], bh1 = bhh[512 + u], bh2 = bhh[1024 + u];
    __syncthreads();

    for (int st = 0; st < nsteps; ++st) {
        const int cur = st & 1, nxt = cur ^ 1;

        // issue gate-input loads EARLY: latency hides under the 512-iter k-loop
        float gx0[4], gx1[4], gx2[4];
#pragma unroll
        for (int r = 0; r < 4; ++r) {
            size_t base = (size_t)((st << 8) + r0 + r) * 1536 + u;
            gx0[r] = gx[base];
            gx1[r] = gx[base + 512];
            gx2[r] = gx[base + 1024];
        }

        float acc0[4] = {0.f,0.f,0.f,0.f};
        float acc1[4] = {0.f,0.f,0.f,0.f};
        float acc2[4] = {0.f,0.f,0.f,0.f};
        const float* wp = whx + u;
#pragma unroll 8
        for (int kk = 0; kk < 512; ++kk) {
            float4 hv = *(const float4*)&sm.rec.hbuf[cur][kk][0];
            float w0 = wp[0], w1 = wp[512], w2 = wp[1024];
            const float* hvp = (const float*)&hv;
#pragma unroll
            for (int r = 0; r < 4; ++r) {
                acc0[r] += w0 * hvp[r];
                acc1[r] += w1 * hvp[r];
                acc2[r] += w2 * hvp[r];
            }
            wp += 1536;
        }

#pragma unroll
        for (int r = 0; r < 4; ++r) {
            float hold = sm.rec.hbuf[cur][u][r];
            float rg = sigmoidf_(gx0[r] + acc0[r] + bh0);
            float zg = sigmoidf_(gx1[r] + acc1[r] + bh1);
            float ng = tanhf(gx2[r] + rg * (acc2[r] + bh2));
            sm.rec.hbuf[nxt][u][r] = (1.f - zg) * ng + zg * hold;
        }
        __syncthreads();
    }

    const int lb = nsteps & 1;
#pragma unroll
    for (int r = 0; r < 4; ++r)
        hTd[(size_t)(r0 + r) * 512 + u] = sm.rec.hbuf[lb][u][r];
}

// ---------------------------------------------------------------------------
__global__ void zerof(float* __restrict__ p, int n)
{
    int i = blockIdx.x * 256 + threadIdx.x;
    if (i < n) p[i] = 0.f;
}

__global__ void init_dec(float* __restrict__ hdec, u16* __restrict__ hbf, int* __restrict__ prev)
{
    int i = blockIdx.x * 256 + threadIdx.x;   // 262144
    hdec[i] = 0.f; hbf[i] = 0;
    if (i < B_) prev[i] = SOS_;
}

// hcat (torch h_n.view quirk): hcat[b][k] = h_dir(b>>7)[(2b)&255 + (k>>9)][k&511]
__global__ void hcat_build(const float* __restrict__ hT, float* __restrict__ hcat)
{
    int idx = blockIdx.x * 256 + threadIdx.x; // 262144
    int b = idx >> 10, k = idx & 1023;
    int d = b >> 7;
    int rr = ((2 * b) & 255) + (k >> 9);
    int kk = k & 511;
    hcat[idx] = hT[(size_t)d * 131072 + (size_t)rr * 512 + kk];
}

// ---------------------------------------------------------------------------
// Prologue-only: gh + gi in one launch.
// ---------------------------------------------------------------------------
__launch_bounds__(256)
__global__ void dec_gemm2(const float* __restrict__ hdec, const int* __restrict__ prev,
                          const float* __restrict__ emb,
                          const float* __restrict__ dwhh, const float* __restrict__ dwih,
                          const float* __restrict__ dbhh, const float* __restrict__ gctx,
                          float* __restrict__ ghbuf, float* __restrict__ gibuf)
{
    constexpr int BK = 32;
    __shared__ float As[BK][68];
    __shared__ float Bs[BK][68];
    const int t  = threadIdx.x;
    const int tx = t & 15, ty = t >> 4;
    const bool isH = blockIdx.y < 4;
    const int m_base = (isH ? blockIdx.y : (blockIdx.y - 4)) * 64;
    const int n_base = blockIdx.x * 64;
    const int K   = isH ? 1024 : 512;
    const float* Bp = isH ? dwhh : dwih;
    const int ldb  = isH ? 1024 : 1600;
    float* Cp = isH ? ghbuf : gibuf;

    float acc[4][4];
#pragma unroll
    for (int i = 0; i < 4; ++i)
#pragma unroll
        for (int j = 0; j < 4; ++j) acc[i][j] = 0.f;

    for (int k0 = 0; k0 < K; k0 += BK) {
#pragma unroll
        for (int j = 0; j < 2; ++j) {
            int f   = t + j * 256;
            int row = f >> 3;
            int kk  = (f & 7) << 2;
            int m   = m_base + row;
            float4 v;
            if (isH) v = ld4(hdec + (size_t)m * HID_ + k0 + kk);
            else     v = ld4(emb + (size_t)prev[m] * EMB_ + k0 + kk);
            As[kk + 0][row] = v.x; As[kk + 1][row] = v.y;
            As[kk + 2][row] = v.z; As[kk + 3][row] = v.w;
            float4 w = ld4(Bp + (size_t)(n_base + row) * ldb + k0 + kk);
            Bs[kk + 0][row] = w.x; Bs[kk + 1][row] = w.y;
            Bs[kk + 2][row] = w.z; Bs[kk + 3][row] = w.w;
        }
        __syncthreads();
#pragma unroll
        for (int kk = 0; kk < BK; ++kk) {
            float a[4], b[4];
            *(float4*)&a[0] = ld4(&As[kk][ty * 4]);
            *(float4*)&b[0] = ld4(&Bs[kk][tx * 4]);
#pragma unroll
            for (int i = 0; i < 4; ++i)
#pragma unroll
                for (int j = 0; j < 4; ++j) acc[i][j] += a[i] * b[j];
        }
        __syncthreads();
    }
#pragma unroll
    for (int i = 0; i < 4; ++i) {
        int m = m_base + ty * 4 + i;
#pragma unroll
        for (int j = 0; j < 4; ++j) {
            int n = n_base + tx * 4 + j;
            float v = acc[i][j];
            if (isH) v += dbhh[n];
            else     v += gctx[(size_t)m * 3072 + n];
            Cp[(size_t)m * 3072 + n] = v;
        }
    }
}

// ---------------------------------------------------------------------------
// gi-only GEMM (steady-state decoder).  grid (48, 4), 256 thr.
// ---------------------------------------------------------------------------
__launch_bounds__(256)
__global__ void dec_gi(const int* __restrict__ prev, const float* __restrict__ emb,
                       const float* __restrict__ dwih, const float* __restrict__ gctx,
                       float* __restrict__ gibuf)
{
    constexpr int BK = 32;
    __shared__ float As[BK][68];
    __shared__ float Bs[BK][68];
    const int t  = threadIdx.x;
    const int tx = t & 15, ty = t >> 4;
    const int m_base = blockIdx.y * 64;
    const int n_base = blockIdx.x * 64;

    float acc[4][4];
#pragma unroll
    for (int i = 0; i < 4; ++i)
#pragma unroll
        for (int j = 0; j < 4; ++j) acc[i][j] = 0.f;

    for (int k0 = 0; k0 < 512; k0 += BK) {
#pragma unroll
        for (int j = 0; j < 2; ++j) {
            int f   = t + j * 256;
            int row = f >> 3;
            int kk  = (f & 7) << 2;
            int m   = m_base + row;
            float4 v = ld4(emb + (size_t)prev[m] * EMB_ + k0 + kk);
            As[kk + 0][row] = v.x; As[kk + 1][row] = v.y;
            As[kk + 2][row] = v.z; As[kk + 3][row] = v.w;
            float4 w = ld4(dwih + (size_t)(n_base + row) * 1600 + k0 + kk);
            Bs[kk + 0][row] = w.x; Bs[kk + 1][row] = w.y;
            Bs[kk + 2][row] = w.z; Bs[kk + 3][row] = w.w;
        }
        __syncthreads();
#pragma unroll
        for (int kk = 0; kk < BK; ++kk) {
            float a[4], b[4];
            *(float4*)&a[0] = ld4(&As[kk][ty * 4]);
            *(float4*)&b[0] = ld4(&Bs[kk][tx * 4]);
#pragma unroll
            for (int i = 0; i < 4; ++i)
#pragma unroll
                for (int j = 0; j < 4; ++j) acc[i][j] += a[i] * b[j];
        }
        __syncthreads();
    }
#pragma unroll
    for (int i = 0; i < 4; ++i) {
        int m = m_base + ty * 4 + i;
#pragma unroll
        for (int j = 0; j < 4; ++j) {
            int n = n_base + tx * 4 + j;
            gibuf[(size_t)m * 3072 + n] = acc[i][j] + gctx[(size_t)m * 3072 + n];
        }
    }
}

__global__ void dec_combine(const float* __restrict__ gi, const float* __restrict__ gh,
                            float* __restrict__ hdec, u16* __restrict__ hbf)
{
    int idx = blockIdx.x * 256 + threadIdx.x;  // 262144
    int b = idx >> 10, u = idx & 1023;
    size_t gb = (size_t)b * 3072;
    float r = sigmoidf_(gi[gb + u]            + gh[gb + u]);
    float z = sigmoidf_(gi[gb + HID_ + u]     + gh[gb + HID_ + u]);
    float n = tanhf    (gi[gb + 2 * HID_ + u] + r * gh[gb + 2 * HID_ + u]);
    float v = (1.f - z) * n + z * hdec[idx];
    hdec[idx] = v;
    hbf[idx] = f2bf(v);
}

// ---------------------------------------------------------------------------
// Fused launch: y==0 -> bf16 MFMA logits + softmax/top2 partials (250 blocks);
// y==1 -> NEXT step's gh GEMM (192 blocks; hdec(t+1) is ready before logits).
// Wbf covers rows [0, wbfRows) with pk2-identical bf16; rest converts inline.
// ---------------------------------------------------------------------------
union DecSM {
    struct { u16 As[256][72]; u16 Bs[128][72]; } lg;   // 55.3 KB
    struct { float As[32][68]; float Bs[32][68]; } gh; // 17.4 KB
};

__launch_bounds__(512)
__global__ void dec_lh(const u16* __restrict__ A, const float* __restrict__ Wf,
                       const u16* __restrict__ Wbf, int wbfRows,
                       const float* __restrict__ bias,
                       float* __restrict__ pmax, float* __restrict__ psum,
                       float* __restrict__ ptv, int* __restrict__ pti,
                       const float* __restrict__ hdec, const float* __restrict__ dwhh,
                       const float* __restrict__ dbhh, float* __restrict__ ghbuf,
                       int doGh)
{
    __shared__ __align__(16) DecSM sm;
    const int t = threadIdx.x;

    if (blockIdx.y == 1) {
        // ---------------- gh GEMM for step t+1 ----------------
        if (!doGh || blockIdx.x >= 192) return;
        const int g  = blockIdx.x;
        const int m0 = (g / 48) * 64;
        const int n0 = (g % 48) * 64;
        const int tx = t & 15, ty = t >> 4;           // ty in [0,32)

        float acc[2][4];
#pragma unroll
        for (int i = 0; i < 2; ++i)
#pragma unroll
            for (int j = 0; j < 4; ++j) acc[i][j] = 0.f;

        for (int k0 = 0; k0 < 1024; k0 += 32) {
            {
                int row = t >> 3;
                int kk  = (t & 7) << 2;
                float4 v = ld4(hdec + (size_t)(m0 + row) * HID_ + k0 + kk);
                sm.gh.As[kk + 0][row] = v.x; sm.gh.As[kk + 1][row] = v.y;
                sm.gh.As[kk + 2][row] = v.z; sm.gh.As[kk + 3][row] = v.w;
                float4 w = ld4(dwhh + (size_t)(n0 + row) * 1024 + k0 + kk);
                sm.gh.Bs[kk + 0][row] = w.x; sm.gh.Bs[kk + 1][row] = w.y;
                sm.gh.Bs[kk + 2][row] = w.z; sm.gh.Bs[kk + 3][row] = w.w;
            }
            __syncthreads();
#pragma unroll
            for (int kk = 0; kk < 32; ++kk) {
                float2 a = *(const float2*)&sm.gh.As[kk][ty * 2];
                float b[4];
                *(float4*)&b[0] = ld4(&sm.gh.Bs[kk][tx * 4]);
#pragma unroll
                for (int j = 0; j < 4; ++j) {
                    acc[0][j] += a.x * b[j];
                    acc[1][j] += a.y * b[j];
                }
            }
            __syncthreads();
        }
#pragma unroll
        for (int i = 0; i < 2; ++i) {
            int m = m0 + ty * 2 + i;
#pragma unroll
            for (int j = 0; j < 4; ++j) {
                int n = n0 + tx * 4 + j;
                ghbuf[(size_t)m * 3072 + n] = acc[i][j] + dbhh[n];
            }
        }
        return;
    }

    // ---------------- logits path ----------------
    const int lane = t & 63, wave = t >> 6;
    const int wm = (wave & 3) * 64, wn = (wave >> 2) * 64;
    const int n0 = blockIdx.x * 128;
    f32x4 acc[4][4];
#pragma unroll
    for (int i = 0; i < 4; ++i)
#pragma unroll
        for (int j = 0; j < 4; ++j) acc[i][j] = (f32x4){0.f, 0.f, 0.f, 0.f};
    const int arow = t >> 1, aoff = (t & 1) * 32;
    const int brow = t >> 2, boff = (t & 3) * 16;
    const bool useBf = (n0 + brow) < wbfRows;

    for (int k0 = 0; k0 < 1024; k0 += 64) {
#pragma unroll
        for (int q = 0; q < 4; ++q) {
            *(uint4*)&sm.lg.As[arow][aoff + q * 8] =
                *(const uint4*)(A + (size_t)arow * 1024 + k0 + aoff + q * 8);
        }
        if (useBf) {
            const u16* wr = Wbf + (size_t)(n0 + brow) * 1024 + k0 + boff;
            *(uint4*)&sm.lg.Bs[brow][boff]     = *(const uint4*)(wr);
            *(uint4*)&sm.lg.Bs[brow][boff + 8] = *(const uint4*)(wr + 8);
        } else {
            const float* wr = Wf + (size_t)(n0 + brow) * 1024 + k0 + boff;
#pragma unroll
            for (int q = 0; q < 2; ++q) {
                float4 x = ld4(wr + q * 8);
                float4 y = ld4(wr + q * 8 + 4);
                uint4 o;
                o.x = pk2(x.x, x.y); o.y = pk2(x.z, x.w);
                o.z = pk2(y.x, y.y); o.w = pk2(y.z, y.w);
                *(uint4*)&sm.lg.Bs[brow][boff + q * 8] = o;
            }
        }
        __syncthreads();
#pragma unroll
        for (int s = 0; s < 2; ++s) {
            short8 a[4], b[4];
            int j0 = s * 32 + (lane >> 4) * 8;
#pragma unroll
            for (int i = 0; i < 4; ++i) {
                a[i] = *(const short8*)&sm.lg.As[wm + i * 16 + (lane & 15)][j0];
                b[i] = *(const short8*)&sm.lg.Bs[wn + i * 16 + (lane & 15)][j0];
            }
#pragma unroll
            for (int i = 0; i < 4; ++i)
#pragma unroll
                for (int j = 0; j < 4; ++j)
                    acc[i][j] = __builtin_amdgcn_mfma_f32_16x16x32_bf16(a[i], b[j], acc[i][j], 0, 0, 0);
        }
        __syncthreads();
    }

    // ---- fused epilogue: per-row (max, sumexp, top2) over this wave's 64 cols
    const int htile = blockIdx.x * 2 + (wn >> 6);
    float bn[4]; int jx[4];
#pragma unroll
    for (int j = 0; j < 4; ++j) { jx[j] = n0 + wn + j * 16 + (lane & 15); bn[j] = bias[jx[j]]; }
#pragma unroll
    for (int i = 0; i < 4; ++i) {
#pragma unroll
        for (int rr = 0; rr < 4; ++rr) {
            float v[4];
#pragma unroll
            for (int j = 0; j < 4; ++j) v[j] = acc[i][j][rr] + bn[j];
            float v1 = v[0], v2 = -3.4e38f; int i1 = jx[0], i2 = 0x7fffffff;
#pragma unroll
            for (int j = 1; j < 4; ++j) {
                if (v[j] > v1)      { v2 = v1; i2 = i1; v1 = v[j]; i1 = jx[j]; }
                else if (v[j] > v2) { v2 = v[j]; i2 = jx[j]; }
            }
#pragma unroll
            for (int mask = 1; mask <= 8; mask <<= 1) {
                float ov1 = __shfl_xor(v1, mask), ov2 = __shfl_xor(v2, mask);
                int   oi1 = __shfl_xor(i1, mask), oi2 = __shfl_xor(i2, mask);
                merge_top2(v1, i1, v2, i2, ov1, oi1, ov2, oi2);
            }
            float rmax = v1;
            float s = 0.f;
#pragma unroll
            for (int j = 0; j < 4; ++j) s += expf(v[j] - rmax);
#pragma unroll
            for (int mask = 1; mask <= 8; mask <<= 1) s += __shfl_xor(s, mask);
            if ((lane & 15) == 0) {
                int row = wm + i * 16 + (lane >> 4) * 4 + rr;
                size_t base = (size_t)row * 500 + htile;
                pmax[base] = rmax; psum[base] = s;
                ptv[base * 2] = v1; ptv[base * 2 + 1] = v2;
                pti[base * 2] = i1; pti[base * 2 + 1] = i2;
            }
        }
    }
}

// ---------------------------------------------------------------------------
// Per-row combine of 500 half-tile partials (unchanged).
// ---------------------------------------------------------------------------
__launch_bounds__(256)
__global__ void dec_reduce(const float* __restrict__ pmax, const float* __restrict__ psum,
                           const float* __restrict__ ptv, const int* __restrict__ pti,
                           const float* __restrict__ hdec, const float* __restrict__ wout,
                           const float* __restrict__ bout,
                           float* __restrict__ out, int* __restrict__ prev, int tstep)
{
    __shared__ float sv[256]; __shared__ int sti[256]; __shared__ int ssl[256];
    __shared__ float cvv[1000]; __shared__ int cii[1000];
    __shared__ float c8v[8]; __shared__ int c8i[8]; __shared__ float c8e[8];
    const int b = blockIdx.x, tid = threadIdx.x;
    const float* pm = pmax + (size_t)b * 500;
    const float* ps = psum + (size_t)b * 500;

    float m = -3.4e38f;
    for (int i = tid; i < 500; i += 256) m = fmaxf(m, pm[i]);
    sv[tid] = m; __syncthreads();
    for (int off = 128; off; off >>= 1) { if (tid < off) sv[tid] = fmaxf(sv[tid], sv[tid + off]); __syncthreads(); }
    float gmax = sv[0]; __syncthreads();

    float s = 0.f;
    for (int i = tid; i < 500; i += 256) s += ps[i] * expf(pm[i] - gmax);
    sv[tid] = s; __syncthreads();
    for (int off = 128; off; off >>= 1) { if (tid < off) sv[tid] += sv[tid + off]; __syncthreads(); }
    float gsum = sv[0]; __syncthreads();

    for (int i = tid; i < 1000; i += 256) { cvv[i] = ptv[(size_t)b * 1000 + i]; cii[i] = pti[(size_t)b * 1000 + i]; }
    __syncthreads();

    for (int c = 0; c < 8; ++c) {
        float bv = -3.4e38f; int bi = 0x7fffffff, bs = 0;
        for (int i = tid; i < 1000; i += 256) {
            float v = cvv[i]; int ix = cii[i];
            if (v > bv || (v == bv && ix < bi)) { bv = v; bi = ix; bs = i; }
        }
        sv[tid] = bv; sti[tid] = bi; ssl[tid] = bs; __syncthreads();
        for (int off = 128; off; off >>= 1) {
            if (tid < off) {
                if (sv[tid + off] > sv[tid] ||
                    (sv[tid + off] == sv[tid] && sti[tid + off] < sti[tid])) {
                    sv[tid] = sv[tid + off]; sti[tid] = sti[tid + off]; ssl[tid] = ssl[tid + off];
                }
            }
            __syncthreads();
        }
        if (tid == 0) { c8v[c] = sv[0]; c8i[c] = sti[0]; cvv[ssl[0]] = -3.4e38f; }
        __syncthreads();
    }

    {   // exact fp32 rescore, 2 candidates per wave
        int lane = tid & 63, wv = tid >> 6;
        const float* hr = hdec + (size_t)b * HID_;
        for (int c = wv; c < 8; c += 4) {
            const float* wr = wout + (size_t)c8i[c] * HID_;
            float a = 0.f;
            for (int k = lane * 4; k < HID_; k += 256) {
                float4 x = ld4(hr + k), y = ld4(wr + k);
                a += x.x * y.x + x.y * y.y + x.z * y.z + x.w * y.w;
            }
#pragma unroll
            for (int off = 32; off; off >>= 1) a += __shfl_down(a, off);
            if (lane == 0) c8e[c] = a + bout[c8i[c]];
        }
    }
    __syncthreads();

    if (tid == 0) {
        float bv = c8e[0]; int bi = c8i[0]; float av = c8v[0];
        for (int c = 1; c < 8; ++c)
            if (c8e[c] > bv || (c8e[c] == bv && c8i[c] < bi)) { bv = c8e[c]; bi = c8i[c]; av = c8v[c]; }
        float p = expf(av - gmax) / gsum;
        float lp = logf(p + 1e-12f);
        out[(size_t)b * TMAX_ + tstep] = (float)bi;
        out[B_ * TMAX_ + (size_t)b * TMAX_ + tstep] = lp;
        prev[b] = bi;
    }
}

// ---------------------------------------------------------------------------
extern "C" void kernel_launch(void* const* d_in, const int* in_sizes, int n_in,
                              void* d_out, int out_size, void* d_ws, size_t ws_size,
                              hipStream_t stream)
{
    const int*   ids   = (const int*)  d_in[0];
    const float* cvec  = (const float*)d_in[1];
    const float* emb   = (const float*)d_in[2];
    const float* wih_f = (const float*)d_in[3];
    const float* whh_f = (const float*)d_in[4];
    const float* bih_f = (const float*)d_in[5];
    const float* bhh_f = (const float*)d_in[6];
    const float* wih_b = (const float*)d_in[7];
    const float* whh_b = (const float*)d_in[8];
    const float* bih_b = (const float*)d_in[9];
    const float* bhh_b = (const float*)d_in[10];
    const float* dwih  = (const float*)d_in[11];
    const float* dwhh  = (const float*)d_in[12];
    const float* dbih  = (const float*)d_in[13];
    const float* dbhh  = (const float*)d_in[14];
    const float* wout  = (const float*)d_in[15];
    const float* bout  = (const float*)d_in[16];
    float* out = (float*)d_out;

    // workspace carve (floats); base total = 15,859,968 f = 63.4 MB.
    float* w      = (float*)d_ws;
    float* buf0_f = w;                          // 3,145,728
    float* buf0_b = w + 3145728;                // 3,145,728
    float* buf1_f = w + 6291456;                // 3,145,728
    float* buf1_b = w + 9437184;                // 3,145,728
    float* hT     = w + 12582912;               // 262,144  [dir][row][unit]
    float* hcat   = w + 12845056;               // 262,144
    float* hdec   = w + 13107200;               // 262,144  LIVE decode
    float* gctx   = w + 13369344;               // 786,432  LIVE decode
    u16*   hdecb  = (u16*)(w + 14155776);       // 131,072 f LIVE decode
    int*   prev   = (int*)(w + 14286848);       // 256       LIVE decode
    float* whhU_f = w + 14287104;               // 786,432
    float* whhU_b = w + 15073536;               // 786,432 -> end 15,859,968
    u16*   wbf_big = (u16*)(w + 15859968);      // optional: 32,768,000 u16
    const int big_ws = (ws_size >= (size_t)(15859968 + 16384000) * 4);
    // --- decode-phase aliases over the dead region [0, 13,107,200) ---
    float* gibuf  = w;                          // 786,432
    float* ghbuf  = w + 786432;                 // 786,432
    float* pmax   = w + 1572864;                // 128,000
    float* psum   = w + 1700864;                // 128,000
    float* ptv    = w + 1828864;                // 256,000
    int*   pti    = (int*)(w + 2084864);        // 256,000
    u16*   wbf_part = (u16*)(w + 2340864);      // 21,495,808 u16 = 10,747,904 f (< 10,766,336 avail)
    const int wbfRows = big_ws ? VOC_ : 20992;  // 20992 = 164 full 128-col tiles
    u16* wbfPtr = big_ws ? wbf_big : wbf_part;

    zerof<<<1024, 256, 0, stream>>>(hT, 262144);
    init_dec<<<1024, 256, 0, stream>>>(hdec, hdecb, prev);
    whh_trans<<<dim3(3072, 2), 256, 0, stream>>>(whh_f, whh_b, whhU_f, whhU_b);

    // ---------------- encoder: 16 chunks x 8 steps, CU-partitioned dispatches ------
    enc_fused<<<768, 512, 0, stream>>>(
        buf0_f, buf0_b, buf0_f, buf0_b, whhU_f, whhU_b, bhh_f, bhh_b,
        wih_f, wih_b, bih_f, bih_b, ids, emb, hT, 0, 0, 8);
    for (int c = 1; c < 16; ++c) {
        float* rf = ((c - 1) & 1) ? buf1_f : buf0_f;
        float* rb = ((c - 1) & 1) ? buf1_b : buf0_b;
        float* of = (c & 1) ? buf1_f : buf0_f;
        float* ob = (c & 1) ? buf1_b : buf0_b;
        enc_fused<<<768, 512, 0, stream>>>(
            rf, rb, of, ob, whhU_f, whhU_b, bhh_f, bhh_b,
            wih_f, wih_b, bih_f, bih_b, ids, emb, hT, 1, c, 8);
    }
    enc_fused<<<768, 512, 0, stream>>>(
        buf1_f, buf1_b, buf1_f, buf1_b, whhU_f, whhU_b, bhh_f, bhh_b,
        wih_f, wih_b, bih_f, bih_b, ids, emb, hT, 1, -1, 8);

    hcat_build<<<1024, 256, 0, stream>>>(hT, hcat);

    // bf16 wout precompute (pk2-identical); encoder buffers are dead now
    {
        int npairs = wbfRows * 512;
        wbf_conv<<<(npairs + 255) / 256, 256, 0, stream>>>(wout, (unsigned*)wbfPtr, npairs);
    }

    // gctx[b][3072] = [hcat|cvec] @ dec_wih[:,512:1600]^T + dbih
    gemm_nt<64, 64, 4, 4, 2, 0, 0><<<dim3(48, 4), 256, 0, stream>>>(
        hcat, nullptr, cvec, dwih, 1600, 512, dbih, nullptr,
        gctx, 3072, 1024, 1088, 0, 0);

    // ---------------- decoder: 40 greedy steps ----------------
    // prologue: gh(0)+gi(0) and combine -> h(1), hb(1)
    dec_gemm2<<<dim3(48, 8), 256, 0, stream>>>(
        hdec, prev, emb, dwhh, dwih, dbhh, gctx, ghbuf, gibuf);
    dec_combine<<<1024, 256, 0, stream>>>(gibuf, ghbuf, hdec, hdecb);
    for (int t = 0; t < TMAX_; ++t) {
        // logits(t) over h(t+1)  ||  gh(t+1) over hdec=h(t+1)  (independent)
        dec_lh<<<dim3(250, 2), 512, 0, stream>>>(
            hdecb, wout, wbfPtr, wbfRows, bout,
            pmax, psum, ptv, pti, hdec, dwhh, dbhh, ghbuf, (t < TMAX_ - 1));
        dec_reduce<<<256, 256, 0, stream>>>(pmax, psum, ptv, pti,
                                            hdec, wout, bout, out, prev, t);
        if (t < TMAX_ - 1) {
            dec_gi<<<dim3(48, 4), 256, 0, stream>>>(prev, emb, dwih, gctx, gibuf);
            dec_combine<<<1024, 256, 0, stream>>>(gibuf, ghbuf, hdec, hdecb);
        }
    }
}